// Round 5
// baseline (68.457 us; speedup 1.0000x reference)
//
#include <hip/hip_runtime.h>
#include <math.h>

#define BB 16
#define KK 5
#define NN 4096
#define DD 1024
#define TOPK 9
#define EPSV 1e-12f
#define RPB 128            // patch rows per block
#define TR 8               // rows per LDS tile (32 KB)
#define NT (RPB / TR)      // 16 tiles per block

typedef float f32x4 __attribute__((ext_vector_type(4)));

// Stage one 8-row (32 KB) tile via global_load_lds: 32 chunks of 1 KB;
// wave w stages chunks w, w+4, ..., w+28. LDS dest is wave-uniform base
// (+ lane*16 applied by HW); global source is per-lane.
__device__ __forceinline__ void stage_tile(const float* g_tile_base,
                                           float* lds_base, int lane, int wid) {
#pragma unroll
  for (int i = 0; i < 8; ++i) {
    int c = wid + i * 4;
    const float* g = g_tile_base + (size_t)(c >> 2) * DD + (c & 3) * 256 + lane * 4;
    __builtin_amdgcn_global_load_lds(
        (const __attribute__((address_space(1))) void*)g,
        (__attribute__((address_space(3))) void*)(lds_base + c * 256),
        16, 0, 0);
  }
}

// ---------------- kernel A: fused cue-norm + sims + patch inv-norms -------
// grid = (N/RPB, B), 256 threads = 4 waves. Double-buffered global_load_lds
// staging (counted vmcnt, raw barriers) keeps 32 KB/block in flight; compute
// reads rows from LDS and does the wave shuffle-reduce.
__global__ __launch_bounds__(256) void sims_kernel(
    const float* __restrict__ patches, const float* __restrict__ cue,
    float* __restrict__ sims, float* __restrict__ invn) {
  int b = blockIdx.y;
  int row0 = blockIdx.x * RPB;
  int wid = threadIdx.x >> 6;
  int lane = threadIdx.x & 63;

  __shared__ float tile[2][TR * DD];  // 2 x 32 KB

  // ---- cue load + in-register normalize (before any staging is issued,
  // so the compiler's cue-data waits drain while the pipe is empty) ----
  float4 c[KK][4];
  const float4* cb = (const float4*)(cue + (size_t)b * KK * DD);
#pragma unroll
  for (int k = 0; k < KK; ++k)
#pragma unroll
    for (int j = 0; j < 4; ++j)
      c[k][j] = cb[k * 256 + j * 64 + lane];
#pragma unroll
  for (int k = 0; k < KK; ++k) {
    float s = c[k][0].x * c[k][0].x + c[k][0].y * c[k][0].y +
              c[k][0].z * c[k][0].z + c[k][0].w * c[k][0].w;
#pragma unroll
    for (int j = 1; j < 4; ++j)
      s += c[k][j].x * c[k][j].x + c[k][j].y * c[k][j].y +
           c[k][j].z * c[k][j].z + c[k][j].w * c[k][j].w;
#pragma unroll
    for (int off = 32; off; off >>= 1) s += __shfl_xor(s, off, 64);
    float inv = 1.0f / fmaxf(sqrtf(s), EPSV);
#pragma unroll
    for (int j = 0; j < 4; ++j) {
      c[k][j].x *= inv; c[k][j].y *= inv;
      c[k][j].z *= inv; c[k][j].w *= inv;
    }
  }

  const float* pbase = patches + (size_t)b * NN * DD + (size_t)row0 * DD;

  // prologue: two tiles in flight (16 loads/wave)
  stage_tile(pbase, tile[0], lane, wid);
  stage_tile(pbase + (size_t)TR * DD, tile[1], lane, wid);

  for (int t = 0; t < NT; ++t) {
    // wait for tile t's loads; keep tile t+1's (8/wave) in flight
    if (t < NT - 1) asm volatile("s_waitcnt vmcnt(8)" ::: "memory");
    else            asm volatile("s_waitcnt vmcnt(0)" ::: "memory");
    __builtin_amdgcn_sched_barrier(0);
    __builtin_amdgcn_s_barrier();
    __builtin_amdgcn_sched_barrier(0);

    const float* buf = tile[t & 1];
#pragma unroll
    for (int rr = 0; rr < 2; ++rr) {
      int r = wid + rr * 4;          // row within tile (waves 0-3 cover 0-7)
      int row = row0 + t * TR + r;   // global patch row
      float acc0 = 0.f, acc1 = 0.f, acc2 = 0.f, acc3 = 0.f, acc4 = 0.f;
      float nr = 0.f;
#pragma unroll
      for (int j = 0; j < 4; ++j) {
        f32x4 p = *(const f32x4*)&buf[r * DD + j * 256 + lane * 4];
        nr += p.x * p.x + p.y * p.y + p.z * p.z + p.w * p.w;
        acc0 += p.x * c[0][j].x + p.y * c[0][j].y + p.z * c[0][j].z + p.w * c[0][j].w;
        acc1 += p.x * c[1][j].x + p.y * c[1][j].y + p.z * c[1][j].z + p.w * c[1][j].w;
        acc2 += p.x * c[2][j].x + p.y * c[2][j].y + p.z * c[2][j].z + p.w * c[2][j].w;
        acc3 += p.x * c[3][j].x + p.y * c[3][j].y + p.z * c[3][j].z + p.w * c[3][j].w;
        acc4 += p.x * c[4][j].x + p.y * c[4][j].y + p.z * c[4][j].z + p.w * c[4][j].w;
      }
#pragma unroll
      for (int off = 32; off; off >>= 1) {
        nr   += __shfl_xor(nr,   off, 64);
        acc0 += __shfl_xor(acc0, off, 64);
        acc1 += __shfl_xor(acc1, off, 64);
        acc2 += __shfl_xor(acc2, off, 64);
        acc3 += __shfl_xor(acc3, off, 64);
        acc4 += __shfl_xor(acc4, off, 64);
      }
      if (lane == 0) {
        float inv = 1.0f / fmaxf(sqrtf(nr), EPSV);
        invn[b * NN + row] = inv;
        sims[((size_t)b * KK + 0) * NN + row] = acc0 * inv;
        sims[((size_t)b * KK + 1) * NN + row] = acc1 * inv;
        sims[((size_t)b * KK + 2) * NN + row] = acc2 * inv;
        sims[((size_t)b * KK + 3) * NN + row] = acc3 * inv;
        sims[((size_t)b * KK + 4) * NN + row] = acc4 * inv;
      }
    }

    // all waves done reading buf[t&1] -> safe to re-stage it
    __builtin_amdgcn_sched_barrier(0);
    __builtin_amdgcn_s_barrier();
    __builtin_amdgcn_sched_barrier(0);
    if (t + 2 < NT)
      stage_tile(pbase + (size_t)(t + 2) * TR * DD, tile[t & 1], lane, wid);
  }
}

// ---------------- kernel B: register top-9 + gather-mean ----------------
__global__ __launch_bounds__(256) void topk_gather_kernel(
    const float* __restrict__ patches, const float* __restrict__ sims,
    const float* __restrict__ invn, float* __restrict__ out) {
  int bk = blockIdx.x;  // 0..B*K
  int b = bk / KK;
  int wid = threadIdx.x >> 6, lane = threadIdx.x & 63;

  unsigned long long key[16];
  const float4* srow = (const float4*)(sims + (size_t)bk * NN);
#pragma unroll
  for (int j = 0; j < 4; ++j) {
    float4 v = srow[j * 256 + threadIdx.x];
    int base = 4 * (j * 256 + threadIdx.x);
    float vv[4] = {v.x, v.y, v.z, v.w};
#pragma unroll
    for (int e = 0; e < 4; ++e) {
      unsigned u = __float_as_uint(vv[e]);
      u = (u & 0x80000000u) ? ~u : (u | 0x80000000u);
      key[j * 4 + e] =
          ((unsigned long long)u << 32) | (unsigned)(~(base + e));
    }
  }

  unsigned long long win[TOPK];
#pragma unroll
  for (int it = 0; it < TOPK; ++it) {
    unsigned long long m = key[0];
#pragma unroll
    for (int j = 1; j < 16; ++j) m = key[j] > m ? key[j] : m;
#pragma unroll
    for (int off = 32; off; off >>= 1) {
      unsigned long long o = __shfl_xor(m, off, 64);
      m = o > m ? o : m;
    }
    win[it] = m;
#pragma unroll
    for (int j = 0; j < 16; ++j)
      if (key[j] == m) key[j] = 0ull;
  }

  __shared__ unsigned long long cand[4 * TOPK];
  __shared__ int sel_idx[TOPK];
  __shared__ float sel_inv[TOPK];
  if (lane == 0) {
#pragma unroll
    for (int it = 0; it < TOPK; ++it) cand[wid * TOPK + it] = win[it];
  }
  __syncthreads();

  if (wid == 0) {
    unsigned long long k2 = (lane < 4 * TOPK) ? cand[lane] : 0ull;
    unsigned long long mm[TOPK];
#pragma unroll
    for (int it = 0; it < TOPK; ++it) {
      unsigned long long m = k2;
#pragma unroll
      for (int off = 32; off; off >>= 1) {
        unsigned long long o = __shfl_xor(m, off, 64);
        m = o > m ? o : m;
      }
      mm[it] = m;
      if (k2 == m) k2 = 0ull;
    }
    if (lane == 0) {
#pragma unroll
      for (int it = 0; it < TOPK; ++it) {
        int idx = (int)(~(unsigned)(mm[it] & 0xFFFFFFFFu));
        sel_idx[it] = idx;
        sel_inv[it] = invn[b * NN + idx];
      }
    }
  }
  __syncthreads();

  const float4* pb = (const float4*)(patches + (size_t)b * NN * DD);
  float4 acc; acc.x = acc.y = acc.z = acc.w = 0.f;
#pragma unroll
  for (int it = 0; it < TOPK; ++it) {
    float inv = sel_inv[it];
    float4 p = pb[(size_t)sel_idx[it] * 256 + threadIdx.x];
    acc.x += p.x * inv; acc.y += p.y * inv;
    acc.z += p.z * inv; acc.w += p.w * inv;
  }
  const float inv9 = 1.0f / 9.0f;
  float4 o;
  o.x = acc.x * inv9; o.y = acc.y * inv9;
  o.z = acc.z * inv9; o.w = acc.w * inv9;
  ((float4*)(out + (size_t)bk * DD))[threadIdx.x] = o;
}

extern "C" void kernel_launch(void* const* d_in, const int* in_sizes, int n_in,
                              void* d_out, int out_size, void* d_ws, size_t ws_size,
                              hipStream_t stream) {
  const float* cue = (const float*)d_in[0];      // (B, K, D) f32
  const float* patches = (const float*)d_in[1];  // (B, N, D) f32
  float* out = (float*)d_out;                    // (B, K, D) f32

  float* invn = (float*)d_ws;                    // B*N   = 65536
  float* sims = invn + (size_t)BB * NN;          // B*K*N = 327680

  dim3 g2(NN / RPB, BB);
  sims_kernel<<<g2, 256, 0, stream>>>(patches, cue, sims, invn);
  topk_gather_kernel<<<BB * KK, 256, 0, stream>>>(patches, sims, invn, out);
}

// Round 6
// 56.728 us; speedup vs baseline: 1.2068x; 1.2068x over previous
//
#include <hip/hip_runtime.h>
#include <math.h>

#define BB 16
#define KK 5
#define NN 4096
#define DD 1024
#define TOPK 9
#define EPSV 1e-12f
#define RPB 64   // patch rows per block in sims kernel

typedef float f32x4 __attribute__((ext_vector_type(4)));

// ---- DPP wave64 reductions (VALU pipe, ~10cy/hop vs ds_bpermute ~120cy) ----
// Sequence shr:1,2,4,8 -> row sums in lane 15 of each 16-row; bcast:15,
// bcast:31 -> full-wave result in lane 63. bound_ctrl=1: OOB lanes read 0.
#define DPP_ADD_F32(x, CTRL)                                                   \
  do {                                                                         \
    int _s = __builtin_amdgcn_update_dpp(0, __float_as_int(x), CTRL, 0xf, 0xf, \
                                         true);                                \
    x += __int_as_float(_s);                                                   \
  } while (0)

__device__ __forceinline__ float wave_sum63(float x) {
  DPP_ADD_F32(x, 0x111);  // row_shr:1
  DPP_ADD_F32(x, 0x112);  // row_shr:2
  DPP_ADD_F32(x, 0x114);  // row_shr:4
  DPP_ADD_F32(x, 0x118);  // row_shr:8
  DPP_ADD_F32(x, 0x142);  // row_bcast:15
  DPP_ADD_F32(x, 0x143);  // row_bcast:31
  return x;  // lane 63 holds the wave sum
}

template <int CTRL>
__device__ __forceinline__ unsigned long long dpp_max_u64_step(
    unsigned long long k) {
  unsigned lo = (unsigned)__builtin_amdgcn_update_dpp(
      0, (int)(unsigned)k, CTRL, 0xf, 0xf, true);
  unsigned hi = (unsigned)__builtin_amdgcn_update_dpp(
      0, (int)(unsigned)(k >> 32), CTRL, 0xf, 0xf, true);
  unsigned long long o = ((unsigned long long)hi << 32) | lo;
  return o > k ? o : k;
}

// full-wave max of u64 keys (keys > 0; 0 is the identity), result uniform
__device__ __forceinline__ unsigned long long wave_max_u64(
    unsigned long long k) {
  k = dpp_max_u64_step<0x111>(k);
  k = dpp_max_u64_step<0x112>(k);
  k = dpp_max_u64_step<0x114>(k);
  k = dpp_max_u64_step<0x118>(k);
  k = dpp_max_u64_step<0x142>(k);
  k = dpp_max_u64_step<0x143>(k);
  unsigned mlo = (unsigned)__builtin_amdgcn_readlane((int)(unsigned)k, 63);
  unsigned mhi =
      (unsigned)__builtin_amdgcn_readlane((int)(unsigned)(k >> 32), 63);
  return ((unsigned long long)mhi << 32) | mlo;
}

// ---------------- kernel A: fused cue-norm + sims + patch inv-norms -------
// grid = (N/RPB, B), 256 threads = 4 waves (R2 structure — best measured).
__global__ __launch_bounds__(256) void sims_kernel(
    const float* __restrict__ patches, const float* __restrict__ cue,
    float* __restrict__ sims, float* __restrict__ invn) {
  int b = blockIdx.y;
  int row0 = blockIdx.x * RPB;
  int wid = threadIdx.x >> 6;
  int lane = threadIdx.x & 63;

  // this lane's cue fragments: 5 cues x 4 float4 = 80 VGPRs
  float4 c[KK][4];
  const float4* cb = (const float4*)(cue + (size_t)b * KK * DD);
#pragma unroll
  for (int k = 0; k < KK; ++k)
#pragma unroll
    for (int j = 0; j < 4; ++j)
      c[k][j] = cb[k * 256 + j * 64 + lane];

  // normalize cues in-register; wave sum via DPP, broadcast via readlane
#pragma unroll
  for (int k = 0; k < KK; ++k) {
    float s = 0.f;
#pragma unroll
    for (int j = 0; j < 4; ++j)
      s += c[k][j].x * c[k][j].x + c[k][j].y * c[k][j].y +
           c[k][j].z * c[k][j].z + c[k][j].w * c[k][j].w;
    s = wave_sum63(s);
    s = __int_as_float(__builtin_amdgcn_readlane(__float_as_int(s), 63));
    float inv = 1.0f / fmaxf(sqrtf(s), EPSV);
#pragma unroll
    for (int j = 0; j < 4; ++j) {
      c[k][j].x *= inv; c[k][j].y *= inv;
      c[k][j].z *= inv; c[k][j].w *= inv;
    }
  }

  const f32x4* pb = (const f32x4*)(patches + (size_t)b * NN * DD);

#pragma unroll 2
  for (int r = wid; r < RPB; r += 4) {
    int row = row0 + r;
    const f32x4* p4 = pb + (size_t)row * 256;
    float acc0 = 0.f, acc1 = 0.f, acc2 = 0.f, acc3 = 0.f, acc4 = 0.f;
    float nr = 0.f;
#pragma unroll
    for (int j = 0; j < 4; ++j) {
      f32x4 p = p4[j * 64 + lane];
      nr += p.x * p.x + p.y * p.y + p.z * p.z + p.w * p.w;
      acc0 += p.x * c[0][j].x + p.y * c[0][j].y + p.z * c[0][j].z + p.w * c[0][j].w;
      acc1 += p.x * c[1][j].x + p.y * c[1][j].y + p.z * c[1][j].z + p.w * c[1][j].w;
      acc2 += p.x * c[2][j].x + p.y * c[2][j].y + p.z * c[2][j].z + p.w * c[2][j].w;
      acc3 += p.x * c[3][j].x + p.y * c[3][j].y + p.z * c[3][j].z + p.w * c[3][j].w;
      acc4 += p.x * c[4][j].x + p.y * c[4][j].y + p.z * c[4][j].z + p.w * c[4][j].w;
    }
    // 6 independent DPP reduce chains (VALU), results land in lane 63
    nr = wave_sum63(nr);
    acc0 = wave_sum63(acc0);
    acc1 = wave_sum63(acc1);
    acc2 = wave_sum63(acc2);
    acc3 = wave_sum63(acc3);
    acc4 = wave_sum63(acc4);
    if (lane == 63) {
      float inv = 1.0f / fmaxf(sqrtf(nr), EPSV);
      invn[b * NN + row] = inv;
      sims[((size_t)b * KK + 0) * NN + row] = acc0 * inv;
      sims[((size_t)b * KK + 1) * NN + row] = acc1 * inv;
      sims[((size_t)b * KK + 2) * NN + row] = acc2 * inv;
      sims[((size_t)b * KK + 3) * NN + row] = acc3 * inv;
      sims[((size_t)b * KK + 4) * NN + row] = acc4 * inv;
    }
  }
}

// ---------------- kernel B: register top-9 + gather-mean ----------------
// grid = B*K blocks, 256 threads = 4 waves. Per-wave top-9 with DPP u64
// max chains; 36->9 merge in wave 0; gather with all 9 loads in flight.
__global__ __launch_bounds__(256) void topk_gather_kernel(
    const float* __restrict__ patches, const float* __restrict__ sims,
    const float* __restrict__ invn, float* __restrict__ out) {
  int bk = blockIdx.x;  // 0..B*K
  int b = bk / KK;
  int wid = threadIdx.x >> 6, lane = threadIdx.x & 63;

  // load the sims row into packed keys: (mapped_f32 << 32) | ~idx
  unsigned long long key[16];
  const float4* srow = (const float4*)(sims + (size_t)bk * NN);
#pragma unroll
  for (int j = 0; j < 4; ++j) {
    float4 v = srow[j * 256 + threadIdx.x];
    int base = 4 * (j * 256 + threadIdx.x);
    float vv[4] = {v.x, v.y, v.z, v.w};
#pragma unroll
    for (int e = 0; e < 4; ++e) {
      unsigned u = __float_as_uint(vv[e]);
      u = (u & 0x80000000u) ? ~u : (u | 0x80000000u);
      key[j * 4 + e] =
          ((unsigned long long)u << 32) | (unsigned)(~(base + e));
    }
  }

  __shared__ unsigned long long cand[4 * TOPK];
  __shared__ int sel_idx[TOPK];
  __shared__ float sel_inv[TOPK];

  // per-wave top-9 (register-only, DPP chains, no block syncs)
#pragma unroll
  for (int it = 0; it < TOPK; ++it) {
    unsigned long long m = key[0];
#pragma unroll
    for (int j = 1; j < 16; ++j) m = key[j] > m ? key[j] : m;
    m = wave_max_u64(m);  // uniform across the wave
    if (lane == 0) cand[wid * TOPK + it] = m;
#pragma unroll
    for (int j = 0; j < 16; ++j)
      if (key[j] == m) key[j] = 0ull;
  }
  __syncthreads();

  // wave 0 merges the 36 candidates -> global top-9
  if (wid == 0) {
    unsigned long long k2 = (lane < 4 * TOPK) ? cand[lane] : 0ull;
#pragma unroll
    for (int it = 0; it < TOPK; ++it) {
      unsigned long long m = wave_max_u64(k2);
      if (k2 == m) k2 = 0ull;
      if (lane == 0) {
        int idx = (int)(~(unsigned)(m & 0xFFFFFFFFu));
        sel_idx[it] = idx;
        sel_inv[it] = invn[b * NN + idx];
      }
    }
  }
  __syncthreads();

  // gather: each thread accumulates one float4 column chunk across 9 rows
  const float4* pb = (const float4*)(patches + (size_t)b * NN * DD);
  float4 acc; acc.x = acc.y = acc.z = acc.w = 0.f;
#pragma unroll
  for (int it = 0; it < TOPK; ++it) {
    float inv = sel_inv[it];
    float4 p = pb[(size_t)sel_idx[it] * 256 + threadIdx.x];
    acc.x += p.x * inv; acc.y += p.y * inv;
    acc.z += p.z * inv; acc.w += p.w * inv;
  }
  const float inv9 = 1.0f / 9.0f;
  float4 o;
  o.x = acc.x * inv9; o.y = acc.y * inv9;
  o.z = acc.z * inv9; o.w = acc.w * inv9;
  ((float4*)(out + (size_t)bk * DD))[threadIdx.x] = o;
}

extern "C" void kernel_launch(void* const* d_in, const int* in_sizes, int n_in,
                              void* d_out, int out_size, void* d_ws, size_t ws_size,
                              hipStream_t stream) {
  const float* cue = (const float*)d_in[0];      // (B, K, D) f32
  const float* patches = (const float*)d_in[1];  // (B, N, D) f32
  float* out = (float*)d_out;                    // (B, K, D) f32

  float* invn = (float*)d_ws;                    // B*N   = 65536
  float* sims = invn + (size_t)BB * NN;          // B*K*N = 327680

  dim3 g2(NN / RPB, BB);
  sims_kernel<<<g2, 256, 0, stream>>>(patches, cue, sims, invn);
  topk_gather_kernel<<<BB * KK, 256, 0, stream>>>(patches, sims, invn, out);
}

// Round 7
// 55.700 us; speedup vs baseline: 1.2290x; 1.0185x over previous
//
#include <hip/hip_runtime.h>
#include <math.h>

#define BB 16
#define KK 5
#define NN 4096
#define DD 1024
#define TOPK 9
#define EPSV 1e-12f
#define RPB 64   // patch rows per block in sims kernel

typedef float f32x4 __attribute__((ext_vector_type(4)));

// ---- DPP wave64 reductions (VALU pipe, ~10cy/hop vs ds_bpermute ~120cy) ----
#define DPP_ADD_F32(x, CTRL)                                                   \
  do {                                                                         \
    int _s = __builtin_amdgcn_update_dpp(0, __float_as_int(x), CTRL, 0xf, 0xf, \
                                         true);                                \
    x += __int_as_float(_s);                                                   \
  } while (0)

__device__ __forceinline__ float wave_sum63(float x) {
  DPP_ADD_F32(x, 0x111);  // row_shr:1
  DPP_ADD_F32(x, 0x112);  // row_shr:2
  DPP_ADD_F32(x, 0x114);  // row_shr:4
  DPP_ADD_F32(x, 0x118);  // row_shr:8
  DPP_ADD_F32(x, 0x142);  // row_bcast:15
  DPP_ADD_F32(x, 0x143);  // row_bcast:31
  return x;  // lane 63 holds the wave sum
}

template <int CTRL>
__device__ __forceinline__ unsigned long long dpp_max_u64_step(
    unsigned long long k) {
  unsigned lo = (unsigned)__builtin_amdgcn_update_dpp(
      0, (int)(unsigned)k, CTRL, 0xf, 0xf, true);
  unsigned hi = (unsigned)__builtin_amdgcn_update_dpp(
      0, (int)(unsigned)(k >> 32), CTRL, 0xf, 0xf, true);
  unsigned long long o = ((unsigned long long)hi << 32) | lo;
  return o > k ? o : k;
}

__device__ __forceinline__ unsigned long long wave_max_u64(
    unsigned long long k) {
  k = dpp_max_u64_step<0x111>(k);
  k = dpp_max_u64_step<0x112>(k);
  k = dpp_max_u64_step<0x114>(k);
  k = dpp_max_u64_step<0x118>(k);
  k = dpp_max_u64_step<0x142>(k);
  k = dpp_max_u64_step<0x143>(k);
  unsigned mlo = (unsigned)__builtin_amdgcn_readlane((int)(unsigned)k, 63);
  unsigned mhi =
      (unsigned)__builtin_amdgcn_readlane((int)(unsigned)(k >> 32), 63);
  return ((unsigned long long)mhi << 32) | mlo;
}

// ---------------- kernel A: fused cue-norm + sims + patch inv-norms -------
// grid = (N/RPB, B), 256 threads = 4 waves. __launch_bounds__(256,4) caps
// VGPR at 128 so all 4 waves/SIMD (= 4 blocks/CU, whole 1024-block grid)
// are co-resident -> no dispatch tail. No unroll-2 (halves live load regs).
__global__ __launch_bounds__(256, 4) void sims_kernel(
    const float* __restrict__ patches, const float* __restrict__ cue,
    float* __restrict__ sims, float* __restrict__ invn) {
  int b = blockIdx.y;
  int row0 = blockIdx.x * RPB;
  int wid = threadIdx.x >> 6;
  int lane = threadIdx.x & 63;

  // this lane's cue fragments: 5 cues x 4 float4 = 80 VGPRs
  float4 c[KK][4];
  const float4* cb = (const float4*)(cue + (size_t)b * KK * DD);
#pragma unroll
  for (int k = 0; k < KK; ++k)
#pragma unroll
    for (int j = 0; j < 4; ++j)
      c[k][j] = cb[k * 256 + j * 64 + lane];

  // normalize cues in-register; wave sum via DPP, broadcast via readlane
#pragma unroll
  for (int k = 0; k < KK; ++k) {
    float s = 0.f;
#pragma unroll
    for (int j = 0; j < 4; ++j)
      s += c[k][j].x * c[k][j].x + c[k][j].y * c[k][j].y +
           c[k][j].z * c[k][j].z + c[k][j].w * c[k][j].w;
    s = wave_sum63(s);
    s = __int_as_float(__builtin_amdgcn_readlane(__float_as_int(s), 63));
    float inv = 1.0f / fmaxf(sqrtf(s), EPSV);
#pragma unroll
    for (int j = 0; j < 4; ++j) {
      c[k][j].x *= inv; c[k][j].y *= inv;
      c[k][j].z *= inv; c[k][j].w *= inv;
    }
  }

  const f32x4* pb = (const f32x4*)(patches + (size_t)b * NN * DD);

  for (int r = wid; r < RPB; r += 4) {
    int row = row0 + r;
    const f32x4* p4 = pb + (size_t)row * 256;
    float acc0 = 0.f, acc1 = 0.f, acc2 = 0.f, acc3 = 0.f, acc4 = 0.f;
    float nr = 0.f;
#pragma unroll
    for (int j = 0; j < 4; ++j) {
      f32x4 p = p4[j * 64 + lane];
      nr += p.x * p.x + p.y * p.y + p.z * p.z + p.w * p.w;
      acc0 += p.x * c[0][j].x + p.y * c[0][j].y + p.z * c[0][j].z + p.w * c[0][j].w;
      acc1 += p.x * c[1][j].x + p.y * c[1][j].y + p.z * c[1][j].z + p.w * c[1][j].w;
      acc2 += p.x * c[2][j].x + p.y * c[2][j].y + p.z * c[2][j].z + p.w * c[2][j].w;
      acc3 += p.x * c[3][j].x + p.y * c[3][j].y + p.z * c[3][j].z + p.w * c[3][j].w;
      acc4 += p.x * c[4][j].x + p.y * c[4][j].y + p.z * c[4][j].z + p.w * c[4][j].w;
    }
    // 6 independent DPP reduce chains (VALU), results land in lane 63
    nr = wave_sum63(nr);
    acc0 = wave_sum63(acc0);
    acc1 = wave_sum63(acc1);
    acc2 = wave_sum63(acc2);
    acc3 = wave_sum63(acc3);
    acc4 = wave_sum63(acc4);
    if (lane == 63) {
      float inv = 1.0f / fmaxf(sqrtf(nr), EPSV);
      invn[b * NN + row] = inv;
      sims[((size_t)b * KK + 0) * NN + row] = acc0 * inv;
      sims[((size_t)b * KK + 1) * NN + row] = acc1 * inv;
      sims[((size_t)b * KK + 2) * NN + row] = acc2 * inv;
      sims[((size_t)b * KK + 3) * NN + row] = acc3 * inv;
      sims[((size_t)b * KK + 4) * NN + row] = acc4 * inv;
    }
  }
}

// ---------------- kernel B: register top-9 + gather-mean ----------------
__global__ __launch_bounds__(256) void topk_gather_kernel(
    const float* __restrict__ patches, const float* __restrict__ sims,
    const float* __restrict__ invn, float* __restrict__ out) {
  int bk = blockIdx.x;  // 0..B*K
  int b = bk / KK;
  int wid = threadIdx.x >> 6, lane = threadIdx.x & 63;

  unsigned long long key[16];
  const float4* srow = (const float4*)(sims + (size_t)bk * NN);
#pragma unroll
  for (int j = 0; j < 4; ++j) {
    float4 v = srow[j * 256 + threadIdx.x];
    int base = 4 * (j * 256 + threadIdx.x);
    float vv[4] = {v.x, v.y, v.z, v.w};
#pragma unroll
    for (int e = 0; e < 4; ++e) {
      unsigned u = __float_as_uint(vv[e]);
      u = (u & 0x80000000u) ? ~u : (u | 0x80000000u);
      key[j * 4 + e] =
          ((unsigned long long)u << 32) | (unsigned)(~(base + e));
    }
  }

  __shared__ unsigned long long cand[4 * TOPK];
  __shared__ int sel_idx[TOPK];
  __shared__ float sel_inv[TOPK];

#pragma unroll
  for (int it = 0; it < TOPK; ++it) {
    unsigned long long m = key[0];
#pragma unroll
    for (int j = 1; j < 16; ++j) m = key[j] > m ? key[j] : m;
    m = wave_max_u64(m);  // uniform across the wave
    if (lane == 0) cand[wid * TOPK + it] = m;
#pragma unroll
    for (int j = 0; j < 16; ++j)
      if (key[j] == m) key[j] = 0ull;
  }
  __syncthreads();

  if (wid == 0) {
    unsigned long long k2 = (lane < 4 * TOPK) ? cand[lane] : 0ull;
#pragma unroll
    for (int it = 0; it < TOPK; ++it) {
      unsigned long long m = wave_max_u64(k2);
      if (k2 == m) k2 = 0ull;
      if (lane == 0) {
        int idx = (int)(~(unsigned)(m & 0xFFFFFFFFu));
        sel_idx[it] = idx;
        sel_inv[it] = invn[b * NN + idx];
      }
    }
  }
  __syncthreads();

  const float4* pb = (const float4*)(patches + (size_t)b * NN * DD);
  float4 acc; acc.x = acc.y = acc.z = acc.w = 0.f;
#pragma unroll
  for (int it = 0; it < TOPK; ++it) {
    float inv = sel_inv[it];
    float4 p = pb[(size_t)sel_idx[it] * 256 + threadIdx.x];
    acc.x += p.x * inv; acc.y += p.y * inv;
    acc.z += p.z * inv; acc.w += p.w * inv;
  }
  const float inv9 = 1.0f / 9.0f;
  float4 o;
  o.x = acc.x * inv9; o.y = acc.y * inv9;
  o.z = acc.z * inv9; o.w = acc.w * inv9;
  ((float4*)(out + (size_t)bk * DD))[threadIdx.x] = o;
}

extern "C" void kernel_launch(void* const* d_in, const int* in_sizes, int n_in,
                              void* d_out, int out_size, void* d_ws, size_t ws_size,
                              hipStream_t stream) {
  const float* cue = (const float*)d_in[0];      // (B, K, D) f32
  const float* patches = (const float*)d_in[1];  // (B, N, D) f32
  float* out = (float*)d_out;                    // (B, K, D) f32

  float* invn = (float*)d_ws;                    // B*N   = 65536
  float* sims = invn + (size_t)BB * NN;          // B*K*N = 327680

  dim3 g2(NN / RPB, BB);
  sims_kernel<<<g2, 256, 0, stream>>>(patches, cue, sims, invn);
  topk_gather_kernel<<<BB * KK, 256, 0, stream>>>(patches, sims, invn, out);
}

// Round 8
// 54.507 us; speedup vs baseline: 1.2559x; 1.0219x over previous
//
#include <hip/hip_runtime.h>
#include <math.h>

#define BB 16
#define KK 5
#define NN 4096
#define DD 1024
#define TOPK 9
#define EPSV 1e-12f
#define RPB 64   // patch rows per block in sims kernel

typedef float f32x4 __attribute__((ext_vector_type(4)));

// ---- DPP wave64 reductions (VALU pipe) ----
#define DPP_ADD_F32(x, CTRL)                                                   \
  do {                                                                         \
    int _s = __builtin_amdgcn_update_dpp(0, __float_as_int(x), CTRL, 0xf, 0xf, \
                                         true);                                \
    x += __int_as_float(_s);                                                   \
  } while (0)

__device__ __forceinline__ float wave_sum63(float x) {
  DPP_ADD_F32(x, 0x111);  // row_shr:1
  DPP_ADD_F32(x, 0x112);  // row_shr:2
  DPP_ADD_F32(x, 0x114);  // row_shr:4
  DPP_ADD_F32(x, 0x118);  // row_shr:8
  DPP_ADD_F32(x, 0x142);  // row_bcast:15
  DPP_ADD_F32(x, 0x143);  // row_bcast:31
  return x;  // lane 63 holds the wave sum
}

template <int CTRL>
__device__ __forceinline__ unsigned long long dpp_max_u64_step(
    unsigned long long k) {
  unsigned lo = (unsigned)__builtin_amdgcn_update_dpp(
      0, (int)(unsigned)k, CTRL, 0xf, 0xf, true);
  unsigned hi = (unsigned)__builtin_amdgcn_update_dpp(
      0, (int)(unsigned)(k >> 32), CTRL, 0xf, 0xf, true);
  unsigned long long o = ((unsigned long long)hi << 32) | lo;
  return o > k ? o : k;
}

__device__ __forceinline__ unsigned long long wave_max_u64(
    unsigned long long k) {
  k = dpp_max_u64_step<0x111>(k);
  k = dpp_max_u64_step<0x112>(k);
  k = dpp_max_u64_step<0x114>(k);
  k = dpp_max_u64_step<0x118>(k);
  k = dpp_max_u64_step<0x142>(k);
  k = dpp_max_u64_step<0x143>(k);
  unsigned mlo = (unsigned)__builtin_amdgcn_readlane((int)(unsigned)k, 63);
  unsigned mhi =
      (unsigned)__builtin_amdgcn_readlane((int)(unsigned)(k >> 32), 63);
  return ((unsigned long long)mhi << 32) | mlo;
}

// ---------------- kernel A: fused cue-norm + sims + patch inv-norms -------
// grid = (N/RPB, B), 256 threads = 4 waves. Cues live in LDS (frees 80
// VGPRs); patch rows flow through a 2-row ping-pong register prefetch so
// next-row loads are in flight during the current row's FMA+reduce.
__global__ __launch_bounds__(256, 4) void sims_kernel(
    const float* __restrict__ patches, const float* __restrict__ cue,
    float* __restrict__ sims, float* __restrict__ invn) {
  int b = blockIdx.y;
  int row0 = blockIdx.x * RPB;
  int wid = threadIdx.x >> 6;
  int lane = threadIdx.x & 63;

  __shared__ float cue_lds[KK * DD];  // 20 KB, normalized cues

  const f32x4* pb = (const f32x4*)(patches + (size_t)b * NN * DD);

  // prologue: issue row-0 loads immediately (don't wait for cue norm)
  const f32x4* pc = pb + (size_t)(row0 + wid) * 256;
  f32x4 cur0 = pc[lane], cur1 = pc[64 + lane], cur2 = pc[128 + lane],
        cur3 = pc[192 + lane];

  // cooperative cue normalize: wave w handles k = w, w+4 (wave0 gets k=4)
  for (int k = wid; k < KK; k += 4) {
    const f32x4* cb = (const f32x4*)(cue + ((size_t)b * KK + k) * DD);
    f32x4 v[4];
#pragma unroll
    for (int j = 0; j < 4; ++j) v[j] = cb[j * 64 + lane];
    float s = 0.f;
#pragma unroll
    for (int j = 0; j < 4; ++j)
      s += v[j].x * v[j].x + v[j].y * v[j].y + v[j].z * v[j].z +
           v[j].w * v[j].w;
    s = wave_sum63(s);
    s = __int_as_float(__builtin_amdgcn_readlane(__float_as_int(s), 63));
    float inv = 1.0f / fmaxf(sqrtf(s), EPSV);
#pragma unroll
    for (int j = 0; j < 4; ++j) {
      f32x4 o;
      o.x = v[j].x * inv; o.y = v[j].y * inv;
      o.z = v[j].z * inv; o.w = v[j].w * inv;
      *(f32x4*)&cue_lds[k * DD + j * 256 + lane * 4] = o;
    }
  }
  __syncthreads();

#pragma unroll 2
  for (int i = 0; i < RPB / 4; ++i) {
    int r = wid + i * 4;
    int row = row0 + r;
    // prefetch next row (last iter re-loads current row: harmless L2 hit)
    int rn = (i < RPB / 4 - 1) ? (r + 4) : r;
    const f32x4* pn = pb + (size_t)(row0 + rn) * 256;
    f32x4 n0 = pn[lane], n1 = pn[64 + lane], n2 = pn[128 + lane],
          n3 = pn[192 + lane];

    float acc0 = 0.f, acc1 = 0.f, acc2 = 0.f, acc3 = 0.f, acc4 = 0.f;
    float nr = 0.f;
    {
      f32x4 p;
#pragma unroll
      for (int j = 0; j < 4; ++j) {
        p = (j == 0) ? cur0 : (j == 1) ? cur1 : (j == 2) ? cur2 : cur3;
        nr += p.x * p.x + p.y * p.y + p.z * p.z + p.w * p.w;
        const float* cl = &cue_lds[j * 256 + lane * 4];
        f32x4 c0 = *(const f32x4*)(cl + 0 * DD);
        f32x4 c1 = *(const f32x4*)(cl + 1 * DD);
        f32x4 c2 = *(const f32x4*)(cl + 2 * DD);
        f32x4 c3 = *(const f32x4*)(cl + 3 * DD);
        f32x4 c4 = *(const f32x4*)(cl + 4 * DD);
        acc0 += p.x * c0.x + p.y * c0.y + p.z * c0.z + p.w * c0.w;
        acc1 += p.x * c1.x + p.y * c1.y + p.z * c1.z + p.w * c1.w;
        acc2 += p.x * c2.x + p.y * c2.y + p.z * c2.z + p.w * c2.w;
        acc3 += p.x * c3.x + p.y * c3.y + p.z * c3.z + p.w * c3.w;
        acc4 += p.x * c4.x + p.y * c4.y + p.z * c4.z + p.w * c4.w;
      }
    }
    // 6 independent DPP reduce chains; results land in lane 63
    nr = wave_sum63(nr);
    acc0 = wave_sum63(acc0);
    acc1 = wave_sum63(acc1);
    acc2 = wave_sum63(acc2);
    acc3 = wave_sum63(acc3);
    acc4 = wave_sum63(acc4);
    if (lane == 63) {
      float inv = 1.0f / fmaxf(sqrtf(nr), EPSV);
      invn[b * NN + row] = inv;
      sims[((size_t)b * KK + 0) * NN + row] = acc0 * inv;
      sims[((size_t)b * KK + 1) * NN + row] = acc1 * inv;
      sims[((size_t)b * KK + 2) * NN + row] = acc2 * inv;
      sims[((size_t)b * KK + 3) * NN + row] = acc3 * inv;
      sims[((size_t)b * KK + 4) * NN + row] = acc4 * inv;
    }
    cur0 = n0; cur1 = n1; cur2 = n2; cur3 = n3;
  }
}

// ---------------- kernel B: register top-9 + gather-mean ----------------
__global__ __launch_bounds__(256) void topk_gather_kernel(
    const float* __restrict__ patches, const float* __restrict__ sims,
    const float* __restrict__ invn, float* __restrict__ out) {
  int bk = blockIdx.x;  // 0..B*K
  int b = bk / KK;
  int wid = threadIdx.x >> 6, lane = threadIdx.x & 63;

  unsigned long long key[16];
  const float4* srow = (const float4*)(sims + (size_t)bk * NN);
#pragma unroll
  for (int j = 0; j < 4; ++j) {
    float4 v = srow[j * 256 + threadIdx.x];
    int base = 4 * (j * 256 + threadIdx.x);
    float vv[4] = {v.x, v.y, v.z, v.w};
#pragma unroll
    for (int e = 0; e < 4; ++e) {
      unsigned u = __float_as_uint(vv[e]);
      u = (u & 0x80000000u) ? ~u : (u | 0x80000000u);
      key[j * 4 + e] =
          ((unsigned long long)u << 32) | (unsigned)(~(base + e));
    }
  }

  __shared__ unsigned long long cand[4 * TOPK];
  __shared__ int sel_idx[TOPK];
  __shared__ float sel_inv[TOPK];

#pragma unroll
  for (int it = 0; it < TOPK; ++it) {
    unsigned long long m = key[0];
#pragma unroll
    for (int j = 1; j < 16; ++j) m = key[j] > m ? key[j] : m;
    m = wave_max_u64(m);  // uniform across the wave
    if (lane == 0) cand[wid * TOPK + it] = m;
#pragma unroll
    for (int j = 0; j < 16; ++j)
      if (key[j] == m) key[j] = 0ull;
  }
  __syncthreads();

  if (wid == 0) {
    unsigned long long k2 = (lane < 4 * TOPK) ? cand[lane] : 0ull;
#pragma unroll
    for (int it = 0; it < TOPK; ++it) {
      unsigned long long m = wave_max_u64(k2);
      if (k2 == m) k2 = 0ull;
      if (lane == 0) {
        int idx = (int)(~(unsigned)(m & 0xFFFFFFFFu));
        sel_idx[it] = idx;
        sel_inv[it] = invn[b * NN + idx];
      }
    }
  }
  __syncthreads();

  const float4* pb = (const float4*)(patches + (size_t)b * NN * DD);
  float4 acc; acc.x = acc.y = acc.z = acc.w = 0.f;
#pragma unroll
  for (int it = 0; it < TOPK; ++it) {
    float inv = sel_inv[it];
    float4 p = pb[(size_t)sel_idx[it] * 256 + threadIdx.x];
    acc.x += p.x * inv; acc.y += p.y * inv;
    acc.z += p.z * inv; acc.w += p.w * inv;
  }
  const float inv9 = 1.0f / 9.0f;
  float4 o;
  o.x = acc.x * inv9; o.y = acc.y * inv9;
  o.z = acc.z * inv9; o.w = acc.w * inv9;
  ((float4*)(out + (size_t)bk * DD))[threadIdx.x] = o;
}

extern "C" void kernel_launch(void* const* d_in, const int* in_sizes, int n_in,
                              void* d_out, int out_size, void* d_ws, size_t ws_size,
                              hipStream_t stream) {
  const float* cue = (const float*)d_in[0];      // (B, K, D) f32
  const float* patches = (const float*)d_in[1];  // (B, N, D) f32
  float* out = (float*)d_out;                    // (B, K, D) f32

  float* invn = (float*)d_ws;                    // B*N   = 65536
  float* sims = invn + (size_t)BB * NN;          // B*K*N = 327680

  dim3 g2(NN / RPB, BB);
  sims_kernel<<<g2, 256, 0, stream>>>(patches, cue, sims, invn);
  topk_gather_kernel<<<BB * KK, 256, 0, stream>>>(patches, sims, invn, out);
}